// Round 1
// baseline (112.765 us; speedup 1.0000x reference)
//
#include <hip/hip_runtime.h>
#include <hip/hip_bf16.h>
#include <cstdint>

// Problem constants
#define Bn 8
#define Cn 64
#define Hn 112
#define Wn 112
#define On 64
#define Ln (Hn * Wn)   // 12544 = 98 * 128
#define HP 114
#define WP 114

typedef __attribute__((ext_vector_type(4))) float f32x4;
typedef __attribute__((ext_vector_type(8))) short bf16x8;
typedef __attribute__((ext_vector_type(4))) unsigned int u32x4;

__device__ __forceinline__ unsigned short f2bf(float f) {
    unsigned u = __float_as_uint(f);
    unsigned r = 0x7fffu + ((u >> 16) & 1u);
    return (unsigned short)((u + r) >> 16);
}

// -----------------------------------------------------------------------------
// Kernel 1: x [B][C][112][112] f32  ->  xpad [B][114][114][C] bf16 (zero border)
// One block per (b, padded-row); one thread per padded-col; loop over channels.
// Reads are lane-coalesced per channel; each thread writes 128B contiguous.
// -----------------------------------------------------------------------------
__global__ __launch_bounds__(128) void prepad_nhwc(const float* __restrict__ x,
                                                   unsigned short* __restrict__ xpad) {
    int bh = blockIdx.x;            // b*114 + hp
    int b = bh / HP, hp = bh - b * HP;
    int wp = threadIdx.x;
    if (wp >= WP) return;
    int h = hp - 1, w = wp - 1;
    bool inb = (h >= 0) & (h < Hn) & (w >= 0) & (w < Wn);
    const float* src = x + ((size_t)b * Cn) * (Hn * Wn) + (inb ? (h * Wn + w) : 0);
    unsigned int buf[32];
#pragma unroll
    for (int c = 0; c < Cn; c += 2) {
        float v0 = src[(size_t)c * (Hn * Wn)];
        float v1 = src[(size_t)(c + 1) * (Hn * Wn)];
        if (!inb) { v0 = 0.f; v1 = 0.f; }
        buf[c >> 1] = (unsigned)f2bf(v0) | ((unsigned)f2bf(v1) << 16);
    }
    u32x4* dst = reinterpret_cast<u32x4*>(xpad + ((size_t)(b * HP + hp) * WP + wp) * Cn);
#pragma unroll
    for (int i = 0; i < 8; i++) {
        u32x4 v;
        v[0] = buf[i * 4 + 0]; v[1] = buf[i * 4 + 1];
        v[2] = buf[i * 4 + 2]; v[3] = buf[i * 4 + 3];
        dst[i] = v;
    }
}

// -----------------------------------------------------------------------------
// Kernel 2: weight [O][C][3][3] f32 -> wpk, bf16 in A-fragment lane order:
//   wpk[fidx][lane][j], fidx = p*8 + of*2 + ki,
//   holds w[o][c][p] with o = of*16 + (lane&15), c = ki*32 + (lane>>4)*8 + j.
// Main loop then loads one 16B chunk per lane -> perfectly shaped A-fragments.
// -----------------------------------------------------------------------------
__global__ __launch_bounds__(64) void wpack_kernel(const float* __restrict__ w,
                                                   unsigned short* __restrict__ wpk) {
    int idx = blockIdx.x;           // [0,72): p*8 + of*2 + ki
    int ki = idx & 1, of = (idx >> 1) & 3, p = idx >> 3;
    int lane = threadIdx.x;
    int o = of * 16 + (lane & 15);
    int cb = ki * 32 + (lane >> 4) * 8;
    unsigned int pk[4];
#pragma unroll
    for (int j = 0; j < 4; j++) {
        float v0 = w[((size_t)o * Cn + cb + 2 * j) * 9 + p];
        float v1 = w[((size_t)o * Cn + cb + 2 * j + 1) * 9 + p];
        pk[j] = (unsigned)f2bf(v0) | ((unsigned)f2bf(v1) << 16);
    }
    u32x4 v; v[0] = pk[0]; v[1] = pk[1]; v[2] = pk[2]; v[3] = pk[3];
    reinterpret_cast<u32x4*>(wpk)[idx * 64 + lane] = v;
}

// -----------------------------------------------------------------------------
// Kernel 3: implicit-GEMM conv with per-pixel tap mask.
// Block = 512 thr (8 waves, wavegrid 2(M=O) x 4(N=pixels)), owns 128 consecutive
// pixels x 64 out-channels of one image. Swapped-operand MFMA:
//   A = weights (M=o), B = x patches (N=pixel) -> D: col(lane&15)=pixel.
// LDS: 4 padded rows [4][114][64] bf16, XOR-swizzled (byte ^= (w&7)<<4),
// staged ONCE; the 9 tap positions are pure LDS address shifts.
// Mask: zero the per-lane B-fragment when mask_idx[pixel] == p.
// -----------------------------------------------------------------------------
__global__ __launch_bounds__(512) void conv_main(const unsigned short* __restrict__ xpad,
                                                 const unsigned short* __restrict__ wpk,
                                                 const int* __restrict__ mask_idx,
                                                 float* __restrict__ out) {
    __shared__ char xs[4 * WP * Cn * 2];   // 58368 B

    int blk = blockIdx.x;
    int b = blk / 98;
    int lt = blk - b * 98;
    int l0 = lt * 128;                      // within-image pixel base
    int oh0 = l0 / Wn;                      // tile spans rows oh0, oh0+1 only

    int tid = threadIdx.x;

    // Stage padded rows oh0..oh0+3 (contiguous in xpad) into LDS, swizzled.
    const u32x4* src = reinterpret_cast<const u32x4*>(
        xpad + ((size_t)(b * HP + oh0) * WP) * Cn);
#pragma unroll
    for (int it = 0; it < 8; it++) {
        int idx = tid + it * 512;           // 16B chunk index, total 3648
        if (idx < 4 * WP * 8) {
            u32x4 v = src[idx];
            int rw = idx >> 3;              // r*114 + w'
            int wq = rw % WP;
            int off = (idx * 16) ^ ((wq & 7) << 4);
            *reinterpret_cast<u32x4*>(xs + off) = v;
        }
    }

    int wave = tid >> 6, lane = tid & 63;
    int wr = wave >> 2;                     // 0..1 : o block of 32
    int wc = wave & 3;                      // 0..3 : pixel block of 32
    int g = lane >> 4, li = lane & 15;

    // Two n-fragments worth of per-lane pixel info
    int pit0 = wc * 32 + li;
    int pit1 = pit0 + 16;
    int lg0 = l0 + pit0, lg1 = l0 + pit1;
    int oh_0 = lg0 / Wn, ow_0 = lg0 - oh_0 * Wn;
    int oh_1 = lg1 / Wn, ow_1 = lg1 - oh_1 * Wn;
    int r0 = oh_0 - oh0, r1 = oh_1 - oh0;   // 0 or 1
    int mv0 = mask_idx[lg0], mv1 = mask_idx[lg1];

    f32x4 acc[2][2] = {};                   // [mi][ni]
    const u32x4* wv = reinterpret_cast<const u32x4*>(wpk);
    const u32x4 vzero = {0u, 0u, 0u, 0u};

    __syncthreads();

    for (int p = 0; p < 9; p++) {
        int dh = p / 3, dw = p - dh * 3;

        // A-fragments (weights) straight from global, L1-hot (72KB total).
        bf16x8 af[2][2];
#pragma unroll
        for (int mi = 0; mi < 2; mi++)
#pragma unroll
            for (int ki = 0; ki < 2; ki++) {
                int fidx = p * 8 + (wr * 2 + mi) * 2 + ki;
                u32x4 raw = wv[fidx * 64 + lane];
                af[mi][ki] = *reinterpret_cast<bf16x8*>(&raw);
            }

        // B-fragments from swizzled LDS; zero whole lane-fragment if masked.
        int wq0 = ow_0 + dw, wq1 = ow_1 + dw;
        int ba0 = ((((r0 + dh) * WP + wq0) << 7) + (g << 4)) ^ ((wq0 & 7) << 4);
        int ba1 = ((((r1 + dh) * WP + wq1) << 7) + (g << 4)) ^ ((wq1 & 7) << 4);
        u32x4 v00 = *reinterpret_cast<const u32x4*>(xs + ba0);
        u32x4 v01 = *reinterpret_cast<const u32x4*>(xs + (ba0 ^ 64));  // ki=1
        u32x4 v10 = *reinterpret_cast<const u32x4*>(xs + ba1);
        u32x4 v11 = *reinterpret_cast<const u32x4*>(xs + (ba1 ^ 64));
        if (mv0 == p) { v00 = vzero; v01 = vzero; }
        if (mv1 == p) { v10 = vzero; v11 = vzero; }
        bf16x8 bf00 = *reinterpret_cast<bf16x8*>(&v00);
        bf16x8 bf01 = *reinterpret_cast<bf16x8*>(&v01);
        bf16x8 bf10 = *reinterpret_cast<bf16x8*>(&v10);
        bf16x8 bf11 = *reinterpret_cast<bf16x8*>(&v11);

#pragma unroll
        for (int mi = 0; mi < 2; mi++) {
            acc[mi][0] = __builtin_amdgcn_mfma_f32_16x16x32_bf16(af[mi][0], bf00, acc[mi][0], 0, 0, 0);
            acc[mi][0] = __builtin_amdgcn_mfma_f32_16x16x32_bf16(af[mi][1], bf01, acc[mi][0], 0, 0, 0);
            acc[mi][1] = __builtin_amdgcn_mfma_f32_16x16x32_bf16(af[mi][0], bf10, acc[mi][1], 0, 0, 0);
            acc[mi][1] = __builtin_amdgcn_mfma_f32_16x16x32_bf16(af[mi][1], bf11, acc[mi][1], 0, 0, 0);
        }
    }

    // Epilogue: D layout col=lane&15 (=pixel), row=(lane>>4)*4+reg (=o).
#pragma unroll
    for (int mi = 0; mi < 2; mi++) {
#pragma unroll
        for (int ni = 0; ni < 2; ni++) {
            int o = wr * 32 + mi * 16 + g * 4;
            int lpix = l0 + wc * 32 + ni * 16 + li;
            float* dst = out + ((size_t)(b * On + o)) * Ln + lpix;
#pragma unroll
            for (int r = 0; r < 4; r++) dst[(size_t)r * Ln] = acc[mi][ni][r];
        }
    }
}

// -----------------------------------------------------------------------------
extern "C" void kernel_launch(void* const* d_in, const int* in_sizes, int n_in,
                              void* d_out, int out_size, void* d_ws, size_t ws_size,
                              hipStream_t stream) {
    const float* x    = (const float*)d_in[0];
    const float* w    = (const float*)d_in[1];
    const int*   mask = (const int*)d_in[2];
    float* out = (float*)d_out;

    unsigned short* xpad = (unsigned short*)d_ws;                          // 13,307,904 B
    unsigned short* wpk  = (unsigned short*)((char*)d_ws +
                                             (size_t)Bn * HP * WP * Cn * 2); // +73,728 B

    prepad_nhwc <<<Bn * HP, 128, 0, stream>>>(x, xpad);
    wpack_kernel<<<72,      64,  0, stream>>>(w, wpk);
    conv_main   <<<Bn * 98, 512, 0, stream>>>(xpad, wpk, mask, out);
}

// Round 2
// 97.479 us; speedup vs baseline: 1.1568x; 1.1568x over previous
//
#include <hip/hip_runtime.h>
#include <hip/hip_bf16.h>
#include <cstdint>

// Problem constants
#define Bn 8
#define Cn 64
#define Hn 112
#define Wn 112
#define On 64
#define Ln (Hn * Wn)   // 12544 = 98 * 128
#define HP 114
#define WP 114

typedef __attribute__((ext_vector_type(4))) float f32x4;
typedef __attribute__((ext_vector_type(8))) short bf16x8;
typedef __attribute__((ext_vector_type(4))) unsigned int u32x4;

__device__ __forceinline__ unsigned f2bf(float f) {
    unsigned u = __float_as_uint(f);
    unsigned r = 0x7fffu + ((u >> 16) & 1u);
    return (u + r) >> 16;   // RNE bf16 in low 16 bits
}

// -----------------------------------------------------------------------------
// Kernel 1: weight [O][C][3][3] f32 -> wpk, bf16 in A-fragment lane order:
//   wpk[fidx][lane][j], fidx = p*8 + wr*4 + mi*2 + ki,
//   holds w[o][c][p] with o = (wr*2+mi)*16 + (lane&15), c = ki*32 + (lane>>4)*8 + j.
// -----------------------------------------------------------------------------
__global__ __launch_bounds__(64) void wpack_kernel(const float* __restrict__ w,
                                                   unsigned short* __restrict__ wpk) {
    int idx = blockIdx.x;           // [0,72): p*8 + of*2 + ki
    int ki = idx & 1, of = (idx >> 1) & 3, p = idx >> 3;
    int lane = threadIdx.x;
    int o = of * 16 + (lane & 15);
    int cb = ki * 32 + (lane >> 4) * 8;
    unsigned int pk[4];
#pragma unroll
    for (int j = 0; j < 4; j++) {
        float v0 = w[((size_t)o * Cn + cb + 2 * j) * 9 + p];
        float v1 = w[((size_t)o * Cn + cb + 2 * j + 1) * 9 + p];
        pk[j] = f2bf(v0) | (f2bf(v1) << 16);
    }
    u32x4 v; v[0] = pk[0]; v[1] = pk[1]; v[2] = pk[2]; v[3] = pk[3];
    reinterpret_cast<u32x4*>(wpk)[idx * 64 + lane] = v;
}

// -----------------------------------------------------------------------------
// Kernel 2: FUSED implicit-GEMM conv with per-pixel tap mask.
// Block = 512 thr (8 waves, 2(O) x 4(pixel) wavegrid), owns 128 consecutive
// pixels x 64 out-channels of one image. Stages 4 padded input rows directly
// from NCHW f32 global into XOR-swizzled NHWC bf16 LDS (58.4 KB), then runs
// the 9-tap x 2-kchunk MFMA loop (taps are pure LDS address shifts).
// A-fragments are prefetched one p ahead (hides L2 latency; wpk > L1).
// XCD pinning: b = blockIdx.x & 7 -> each image's 3.2MB x-slab stays in one
// XCD's L2 across the 3.4x row re-reads.
// -----------------------------------------------------------------------------
__global__ __launch_bounds__(512) void conv_fused(const float* __restrict__ x,
                                                  const unsigned short* __restrict__ wpk,
                                                  const int* __restrict__ mask_idx,
                                                  float* __restrict__ out) {
    __shared__ char xs[4 * WP * Cn * 2];   // 58368 B, layout [row][wp][c] bf16, 16B-swizzled

    int b  = blockIdx.x & 7;                // image -> XCD pin
    int lt = blockIdx.x >> 3;               // 0..97
    int l0 = lt * 128;                      // within-image pixel base
    int oh0 = l0 / Wn;                      // tile spans output rows oh0, oh0+1

    int tid = threadIdx.x;

    // ---- Staging: NCHW f32 -> swizzled NHWC bf16 LDS -----------------------
    // 16B chunk = (row, wp, c8): load order q = (row*8 + c8)*114 + wp so lanes
    // step wp (coalesced 456B row segments per (row, channel)).
    const float* xb = x + (size_t)b * Cn * Hn * Wn;
#pragma unroll
    for (int it = 0; it < 8; ++it) {
        int q = tid + it * 512;
        if (q < 4 * 8 * WP) {               // 3648
            int row = q / (8 * WP);
            int rem = q - row * (8 * WP);
            int c8  = rem / WP;
            int wp  = rem - c8 * WP;
            int h = oh0 + row - 1;
            int w = wp - 1;
            bool inb = ((unsigned)h < (unsigned)Hn) & ((unsigned)w < (unsigned)Wn);
            const float* s = xb + ((size_t)(c8 * 8) * Hn + (inb ? h : 0)) * Wn + (inb ? w : 0);
            unsigned pk[4];
#pragma unroll
            for (int j = 0; j < 4; ++j) {
                float v0 = s[(size_t)(2 * j)     * (Hn * Wn)];
                float v1 = s[(size_t)(2 * j + 1) * (Hn * Wn)];
                if (!inb) { v0 = 0.f; v1 = 0.f; }
                pk[j] = f2bf(v0) | (f2bf(v1) << 16);
            }
            int qs = (row * WP + wp) * 8 + c8;          // LDS chunk index
            int off = (qs * 16) ^ ((wp & 7) << 4);      // write-side swizzle
            u32x4 v; v[0] = pk[0]; v[1] = pk[1]; v[2] = pk[2]; v[3] = pk[3];
            *reinterpret_cast<u32x4*>(xs + off) = v;
        }
    }

    // ---- Per-lane geometry -------------------------------------------------
    int wave = tid >> 6, lane = tid & 63;
    int wr = wave >> 2;                     // 0..1 : o block of 32
    int wc = wave & 3;                      // 0..3 : pixel block of 32
    int g = lane >> 4, li = lane & 15;

    int pit0 = wc * 32 + li;
    int pit1 = pit0 + 16;
    int lg0 = l0 + pit0, lg1 = l0 + pit1;
    int oh_0 = lg0 / Wn, ow_0 = lg0 - oh_0 * Wn;
    int oh_1 = lg1 / Wn, ow_1 = lg1 - oh_1 * Wn;
    int r0 = oh_0 - oh0, r1 = oh_1 - oh0;   // 0 or 1
    int mv0 = mask_idx[lg0], mv1 = mask_idx[lg1];

    f32x4 acc[2][2] = {};                   // [mi][ni]
    const u32x4* wv = reinterpret_cast<const u32x4*>(wpk);
    const u32x4 vzero = {0u, 0u, 0u, 0u};

    // Prefetch p=0 A-fragments (fidx = p*8 + wr*4 + mi*2 + ki)
    u32x4 an[4];
#pragma unroll
    for (int f = 0; f < 4; ++f) an[f] = wv[(wr * 4 + f) * 64 + lane];

    __syncthreads();

    for (int p = 0; p < 9; ++p) {
        int dh = p / 3, dw = p - dh * 3;

        // Grab current A-frags, then prefetch next p's (L2 latency hides
        // under this iteration's LDS reads + MFMAs).
        u32x4 ac[4] = {an[0], an[1], an[2], an[3]};
        if (p < 8) {
#pragma unroll
            for (int f = 0; f < 4; ++f)
                an[f] = wv[((p + 1) * 8 + wr * 4 + f) * 64 + lane];
        }
        bf16x8 af[2][2];
        af[0][0] = *reinterpret_cast<bf16x8*>(&ac[0]);
        af[0][1] = *reinterpret_cast<bf16x8*>(&ac[1]);
        af[1][0] = *reinterpret_cast<bf16x8*>(&ac[2]);
        af[1][1] = *reinterpret_cast<bf16x8*>(&ac[3]);

        // B-fragments from swizzled LDS; zero whole lane-fragment if masked.
        int wq0 = ow_0 + dw, wq1 = ow_1 + dw;
        int ba0 = ((((r0 + dh) * WP + wq0) << 7) + (g << 4)) ^ ((wq0 & 7) << 4);
        int ba1 = ((((r1 + dh) * WP + wq1) << 7) + (g << 4)) ^ ((wq1 & 7) << 4);
        u32x4 v00 = *reinterpret_cast<const u32x4*>(xs + ba0);
        u32x4 v01 = *reinterpret_cast<const u32x4*>(xs + (ba0 ^ 64));  // ki=1
        u32x4 v10 = *reinterpret_cast<const u32x4*>(xs + ba1);
        u32x4 v11 = *reinterpret_cast<const u32x4*>(xs + (ba1 ^ 64));
        if (mv0 == p) { v00 = vzero; v01 = vzero; }
        if (mv1 == p) { v10 = vzero; v11 = vzero; }
        bf16x8 bf00 = *reinterpret_cast<bf16x8*>(&v00);
        bf16x8 bf01 = *reinterpret_cast<bf16x8*>(&v01);
        bf16x8 bf10 = *reinterpret_cast<bf16x8*>(&v10);
        bf16x8 bf11 = *reinterpret_cast<bf16x8*>(&v11);

#pragma unroll
        for (int mi = 0; mi < 2; mi++) {
            acc[mi][0] = __builtin_amdgcn_mfma_f32_16x16x32_bf16(af[mi][0], bf00, acc[mi][0], 0, 0, 0);
            acc[mi][0] = __builtin_amdgcn_mfma_f32_16x16x32_bf16(af[mi][1], bf01, acc[mi][0], 0, 0, 0);
            acc[mi][1] = __builtin_amdgcn_mfma_f32_16x16x32_bf16(af[mi][0], bf10, acc[mi][1], 0, 0, 0);
            acc[mi][1] = __builtin_amdgcn_mfma_f32_16x16x32_bf16(af[mi][1], bf11, acc[mi][1], 0, 0, 0);
        }
    }

    // Epilogue: D layout col=lane&15 (=pixel), row=(lane>>4)*4+reg (=o).
#pragma unroll
    for (int mi = 0; mi < 2; mi++) {
#pragma unroll
        for (int ni = 0; ni < 2; ni++) {
            int o = wr * 32 + mi * 16 + g * 4;
            int lpix = l0 + wc * 32 + ni * 16 + li;
            float* dst = out + ((size_t)(b * On + o)) * Ln + lpix;
#pragma unroll
            for (int r = 0; r < 4; r++) dst[(size_t)r * Ln] = acc[mi][ni][r];
        }
    }
}

// -----------------------------------------------------------------------------
extern "C" void kernel_launch(void* const* d_in, const int* in_sizes, int n_in,
                              void* d_out, int out_size, void* d_ws, size_t ws_size,
                              hipStream_t stream) {
    const float* x    = (const float*)d_in[0];
    const float* w    = (const float*)d_in[1];
    const int*   mask = (const int*)d_in[2];
    float* out = (float*)d_out;

    unsigned short* wpk = (unsigned short*)d_ws;   // 73,728 B

    wpack_kernel<<<72,      64,  0, stream>>>(w, wpk);
    conv_fused  <<<Bn * 98, 512, 0, stream>>>(x, wpk, mask, out);
}

// Round 4
// 95.285 us; speedup vs baseline: 1.1835x; 1.0230x over previous
//
#include <hip/hip_runtime.h>
#include <hip/hip_bf16.h>
#include <cstdint>

// Problem constants
#define Bn 8
#define Cn 64
#define Hn 112
#define Wn 112
#define On 64
#define Ln (Hn * Wn)   // 12544 = 98 * 128
#define HP 114
#define WP 114

typedef __attribute__((ext_vector_type(4)))  float f32x4;
typedef __attribute__((ext_vector_type(16))) float f32x16;
typedef __attribute__((ext_vector_type(8)))  short bf16x8;
typedef __attribute__((ext_vector_type(4)))  unsigned int u32x4;

__device__ __forceinline__ unsigned f2bf(float f) {
    unsigned u = __float_as_uint(f);
    unsigned r = 0x7fffu + ((u >> 16) & 1u);
    return (u + r) >> 16;   // RNE bf16 in low 16 bits
}

// -----------------------------------------------------------------------------
// Kernel 1: weight [O][C][3][3] f32 -> wpk, bf16 in 32x32x16 A-fragment order:
//   frag idx = (p*2 + wr)*4 + kc ; per lane (of 64):
//     o = wr*32 + (lane&31),  c = kc*16 + (lane>>5)*8 + j   (j = 0..7)
// Main loop loads one 16B chunk per lane -> exact A-fragment for
// v_mfma_f32_32x32x16_bf16.
// -----------------------------------------------------------------------------
__global__ __launch_bounds__(64) void wpack_kernel(const float* __restrict__ w,
                                                   unsigned short* __restrict__ wpk) {
    int idx = blockIdx.x;             // [0,72) = (p*2 + wr)*4 + kc
    int kc = idx & 3, wr = (idx >> 2) & 1, p = idx >> 3;
    int lane = threadIdx.x;
    int o  = wr * 32 + (lane & 31);
    int cb = kc * 16 + (lane >> 5) * 8;
    unsigned pk[4];
#pragma unroll
    for (int j = 0; j < 4; j++) {
        float v0 = w[((size_t)o * Cn + cb + 2 * j) * 9 + p];
        float v1 = w[((size_t)o * Cn + cb + 2 * j + 1) * 9 + p];
        pk[j] = f2bf(v0) | (f2bf(v1) << 16);
    }
    u32x4 v; v[0] = pk[0]; v[1] = pk[1]; v[2] = pk[2]; v[3] = pk[3];
    reinterpret_cast<u32x4*>(wpk)[idx * 64 + lane] = v;
}

// -----------------------------------------------------------------------------
// Kernel 2: FUSED implicit-GEMM conv, 32x32x16 MFMA, per-pixel tap mask.
// Block = 512 thr (8 waves: 2(O) x 4(pixel)), owns 128 consecutive pixels x
// 64 out-channels of one image. Stages 4 padded input rows NCHW f32 ->
// XOR-swizzled NHWC bf16 LDS (58.4 KB). 9 taps = pure LDS address shifts.
// One 32(o) x 32(px) acc tile per wave; one pixel per lane.
// A-fragments prefetched 2 deep (static apre[2][4], fully unrolled p-loop).
// __launch_bounds__(512,4): cap 128 VGPR -> 2 blocks/CU (117KB LDS fits).
// XCD pinning: b = blockIdx.x & 7.
// -----------------------------------------------------------------------------
__global__ __launch_bounds__(512, 4) void conv_fused(const float* __restrict__ x,
                                                     const unsigned short* __restrict__ wpk,
                                                     const int* __restrict__ mask_idx,
                                                     float* __restrict__ out) {
    __shared__ char xs[4 * WP * Cn * 2];   // 58368 B, [row][wp][c] bf16, 16B-slot swizzle

    int b  = blockIdx.x & 7;                // image -> XCD pin
    int lt = blockIdx.x >> 3;               // 0..97
    int l0 = lt * 128;
    int oh0 = l0 / Wn;                      // tile spans output rows oh0, oh0+1

    int tid  = threadIdx.x;
    int wave = tid >> 6, lane = tid & 63;
    int wr = wave >> 2;                     // 0..1 : o block of 32
    int wc = wave & 3;                      // 0..3 : pixel block of 32
    int hi = lane >> 5;

    int lg = l0 + wc * 32 + (lane & 31);    // this lane's pixel
    int oh = lg / Wn, ow = lg - oh * Wn;
    int r  = oh - oh0;                      // 0 or 1
    int mv = mask_idx[lg];

    // Prefetch p=0,1 A-fragments before staging (independent L2 traffic).
    const u32x4* wv = reinterpret_cast<const u32x4*>(wpk);
    u32x4 apre[2][4];
#pragma unroll
    for (int kc = 0; kc < 4; ++kc) apre[0][kc] = wv[((0 * 2 + wr) * 4 + kc) * 64 + lane];
#pragma unroll
    for (int kc = 0; kc < 4; ++kc) apre[1][kc] = wv[((1 * 2 + wr) * 4 + kc) * 64 + lane];

    // ---- Staging: NCHW f32 -> swizzled NHWC bf16 LDS -----------------------
    const float* xb = x + (size_t)b * Cn * Hn * Wn;
#pragma unroll
    for (int it = 0; it < 8; ++it) {
        int q = tid + it * 512;
        if (q < 4 * 8 * WP) {               // 3648 16B chunks
            int row = q / (8 * WP);
            int rem = q - row * (8 * WP);
            int c8  = rem / WP;
            int wp  = rem - c8 * WP;
            int h = oh0 + row - 1;
            int w = wp - 1;
            bool inb = ((unsigned)h < (unsigned)Hn) & ((unsigned)w < (unsigned)Wn);
            const float* s = xb + ((size_t)(c8 * 8) * Hn + (inb ? h : 0)) * Wn + (inb ? w : 0);
            unsigned pk[4];
#pragma unroll
            for (int j = 0; j < 4; ++j) {
                float v0 = s[(size_t)(2 * j)     * (Hn * Wn)];
                float v1 = s[(size_t)(2 * j + 1) * (Hn * Wn)];
                if (!inb) { v0 = 0.f; v1 = 0.f; }
                pk[j] = f2bf(v0) | (f2bf(v1) << 16);
            }
            int qs = (row * WP + wp) * 8 + c8;          // 16B slot index
            int off = (qs * 16) ^ ((wp & 7) << 4);      // write-side swizzle
            u32x4 v; v[0] = pk[0]; v[1] = pk[1]; v[2] = pk[2]; v[3] = pk[3];
            *reinterpret_cast<u32x4*>(xs + off) = v;
        }
    }

    f32x16 acc = {};
    const u32x4 vzero = {0u, 0u, 0u, 0u};

    __syncthreads();

#pragma unroll
    for (int p = 0; p < 9; ++p) {
        int dh = p / 3, dw = p - dh * 3;

        // B-fragments: lane's pixel, 4 k-chunks of 16 channels.
        int wq   = ow + dw;
        int base = ((r + dh) * WP + wq) << 7;
        int swz  = (wq & 7) << 4;
        u32x4 bv[4];
#pragma unroll
        for (int kc = 0; kc < 4; ++kc) {
            int off = (base + ((2 * kc + hi) << 4)) ^ swz;
            bv[kc] = *reinterpret_cast<const u32x4*>(xs + off);
        }
        if (mv == p) { bv[0] = vzero; bv[1] = vzero; bv[2] = vzero; bv[3] = vzero; }

#pragma unroll
        for (int kc = 0; kc < 4; ++kc) {
            bf16x8 a = *reinterpret_cast<bf16x8*>(&apre[p & 1][kc]);
            bf16x8 bb = *reinterpret_cast<bf16x8*>(&bv[kc]);
            acc = __builtin_amdgcn_mfma_f32_32x32x16_bf16(a, bb, acc, 0, 0, 0);
        }

        // Prefetch p+2's A-fragments into the slot just consumed.
        if (p < 7) {
#pragma unroll
            for (int kc = 0; kc < 4; ++kc)
                apre[p & 1][kc] = wv[(((p + 2) * 2 + wr) * 4 + kc) * 64 + lane];
        }
    }

    // Epilogue: D layout col=lane&31 (=pixel), row=(reg&3)+8*(reg>>2)+4*hi (=o).
    float* ob = out + (size_t)(b * On + wr * 32) * Ln + lg;
#pragma unroll
    for (int reg = 0; reg < 16; ++reg) {
        int orow = (reg & 3) + 8 * (reg >> 2) + 4 * hi;
        ob[(size_t)orow * Ln] = acc[reg];
    }
}

// -----------------------------------------------------------------------------
extern "C" void kernel_launch(void* const* d_in, const int* in_sizes, int n_in,
                              void* d_out, int out_size, void* d_ws, size_t ws_size,
                              hipStream_t stream) {
    const float* x    = (const float*)d_in[0];
    const float* w    = (const float*)d_in[1];
    const int*   mask = (const int*)d_in[2];
    float* out = (float*)d_out;

    unsigned short* wpk = (unsigned short*)d_ws;   // 73,728 B

    wpack_kernel<<<72,      64,  0, stream>>>(w, wpk);
    conv_fused  <<<Bn * 98, 512, 0, stream>>>(x, wpk, mask, out);
}